// Round 10
// baseline (144.636 us; speedup 1.0000x reference)
//
#include <hip/hip_runtime.h>
#include <stdint.h>

// Dims: msa[1,S,R,M] fp32 ; left_w/right_w[M,C] ; out_w[C*C,CZ] ; out[1,R,R,CZ] fp32
#define S_DIM 128
#define R_DIM 256
#define M_DIM 256
#define C_DIM 32
#define CZ_DIM 128
#define K2_DIM 1024  // C*C

typedef _Float16 f16;
typedef _Float16 f16x4 __attribute__((ext_vector_type(4)));
typedef _Float16 f16x8 __attribute__((ext_vector_type(8)));
typedef float f32x4 __attribute__((ext_vector_type(4)));
typedef float f32x16 __attribute__((ext_vector_type(16)));

#define MFMA32(a, b, c) __builtin_amdgcn_mfma_f32_32x32x16_f16(a, b, c, 0, 0, 0)

// ---------------------------------------------------------------------------
// prep: weights -> f16.
//  wt_l/wt_r[c][m] (proj A-operands).
//  wt2 = out_w in c-half-major stage2 B-fragment order:
//   c = k2>>5, e = k2&31, X = c>>4 (c-half), cl = c&15,
//   k2ph = (e>>2)*64 + cl*4 + (e&3)   (k-perm within the 512-wide half)
//   kk = k2ph>>4, q5 = (k2ph>>3)&1, j = k2ph&7, ntile = cz>>5, l31 = cz&31
//   idx = ((X*4+ntile)*32 + kk)*512 + (l31*2+q5)*8 + j   -> 1KB/wave coalesced.
// ---------------------------------------------------------------------------
__global__ void prep_kernel(const float* __restrict__ lw, const float* __restrict__ rw,
                            const float* __restrict__ ow,
                            f16* __restrict__ wt_l, f16* __restrict__ wt_r,
                            f16* __restrict__ wt2) {
    int idx = blockIdx.x * blockDim.x + threadIdx.x;
    int stride = gridDim.x * blockDim.x;
    for (int i = idx; i < CZ_DIM * K2_DIM; i += stride) {
        int cz = i >> 10, k2 = i & 1023;
        int c = k2 >> 5, e = k2 & 31;
        int X = c >> 4, cl = c & 15;
        int k2ph = ((e >> 2) << 6) + (cl << 2) + (e & 3);
        int kk = k2ph >> 4, q5 = (k2ph >> 3) & 1, j = k2ph & 7;
        int ntile = cz >> 5, l31 = cz & 31;
        wt2[(((X * 4 + ntile) * 32) + kk) * 512 + (l31 * 2 + q5) * 8 + j] =
            (f16)ow[k2 * CZ_DIM + cz];
    }
    for (int i = idx; i < C_DIM * M_DIM; i += stride) {
        int c = i >> 8, m = i & 255;
        wt_l[i] = (f16)lw[m * C_DIM + c];
        wt_r[i] = (f16)rw[m * C_DIM + c];
    }
}

// ---------------------------------------------------------------------------
// proj (unchanged, near HBM floor): left_t[(r*32+c)][s] row-major;
// rt2 in stage1 A-fragment-major order.
// ---------------------------------------------------------------------------
__global__ __launch_bounds__(256, 4)
void proj_kernel(const float* __restrict__ msa, const f16* __restrict__ wt_l,
                 const f16* __restrict__ wt_r,
                 f16* __restrict__ left_t, f16* __restrict__ rt2) {
    int bid = blockIdx.x;            // 512 = 256 r * 2 s-halves
    int r  = bid >> 1;
    int s0 = (bid & 1) << 6;
    int tid = threadIdx.x;
    int w = tid >> 6;
    int lane = tid & 63;
    int q = lane >> 4, li = lane & 15;

    int s_col = s0 + w * 16 + li;
    const f32x4* bp = (const f32x4*)(msa + ((size_t)s_col * R_DIM + r) * M_DIM + q * 8);

    f32x4 b[16];
#pragma unroll
    for (int ks = 0; ks < 8; ks++) { b[2 * ks] = bp[ks * 8]; b[2 * ks + 1] = bp[ks * 8 + 1]; }

    f32x4 aL0 = {0,0,0,0}, aL1 = {0,0,0,0}, aR0 = {0,0,0,0}, aR1 = {0,0,0,0};
#pragma unroll
    for (int ks = 0; ks < 8; ks++) {
        f16x8 bf;
#pragma unroll
        for (int u = 0; u < 4; u++) { bf[u] = (f16)b[2*ks][u]; bf[4 + u] = (f16)b[2*ks+1][u]; }
        const f16* a0 = wt_l + li * M_DIM + ks * 32 + q * 8;
        const f16* a1 = wt_r + li * M_DIM + ks * 32 + q * 8;
        f16x8 al0 = *(const f16x8*)(a0);
        f16x8 al1 = *(const f16x8*)(a0 + 16 * M_DIM);
        f16x8 ar0 = *(const f16x8*)(a1);
        f16x8 ar1 = *(const f16x8*)(a1 + 16 * M_DIM);
        aL0 = __builtin_amdgcn_mfma_f32_16x16x32_f16(al0, bf, aL0, 0, 0, 0);
        aL1 = __builtin_amdgcn_mfma_f32_16x16x32_f16(al1, bf, aL1, 0, 0, 0);
        aR0 = __builtin_amdgcn_mfma_f32_16x16x32_f16(ar0, bf, aR0, 0, 0, 0);
        aR1 = __builtin_amdgcn_mfma_f32_16x16x32_f16(ar1, bf, aR1, 0, 0, 0);
    }
    int ks_s = s_col >> 4, q5_s = (s_col >> 3) & 1, j_s = s_col & 7;
    int sbase = (r * 8 + ks_s) * 512 + q5_s * 8 + j_s;
#pragma unroll
    for (int reg = 0; reg < 4; reg++) {
        int c0 = q * 4 + reg;
        left_t[(r * C_DIM + c0) * S_DIM + s_col]      = (f16)aL0[reg];
        left_t[(r * C_DIM + c0 + 16) * S_DIM + s_col] = (f16)aL1[reg];
        rt2[sbase + c0 * 16]        = (f16)aR0[reg];
        rt2[sbase + (c0 + 16) * 16] = (f16)aR1[reg];
    }
}

// ---------------------------------------------------------------------------
// fuse_kernel v6: c-split two-round pipeline.
//  LDS regions: [0:32K] = c<16 half (staging rows, later outerA overlay),
//               [32K:64K] = c>=16 half (staging rows, later outerB overlay).
//  Staging rows hrow = r*16 + cl (r=0..7, cl=0..15), 256B/row, XOR swizzle.
//  Round X: phase1-X (16 MFMA) -> barrier -> phase2-X (outer overlay, rows
//  p*1KB, chunk phys=(chunk+p)&63) -> barrier -> stage2-X (16 MFMA + W).
//  stage2-A is immediately followed (no barrier) by phase1-B: disjoint
//  regions, both read-only -> scheduler mixes W loads, LDS reads, 2 MFMA
//  streams. accP/accQ accumulate across both rounds; reduction as before.
// ---------------------------------------------------------------------------
__device__ __forceinline__ void phase1_half(const f16* stg, const f16x8* afr,
                                            int rg4, int l31, int q5, int lx,
                                            f32x16* acc) {
#pragma unroll
    for (int i = 0; i < 2; i++) {
        const f16* bbase = stg + ((rg4 * 2 + i) * 32 + l31) * 128;
#pragma unroll
        for (int ks = 0; ks < 8; ks++) {
            f16x8 bfr = *(const f16x8*)(bbase + (((2 * ks + q5) ^ lx) << 3));
            acc[i] = MFMA32(afr[ks], bfr, acc[i]);
        }
    }
}

__device__ __forceinline__ void phase2_half(char* region, const f32x16* acc,
                                            int rg4, int t_tile, int l31, int q5) {
    int cl = l31 & 15, r_hi = l31 >> 4;
#pragma unroll
    for (int i = 0; i < 2; i++) {
        int p = ((rg4 * 2 + i) * 2 + r_hi) * 4 + t_tile;   // pair row 0..31
        char* prow = region + p * 1024;
#pragma unroll
        for (int rg = 0; rg < 4; rg++) {
            int chunk = (2 * rg + q5) * 8 + (cl >> 1);
            int phys = (chunk + p) & 63;
            f16x4 h = {(f16)acc[i][4 * rg], (f16)acc[i][4 * rg + 1],
                       (f16)acc[i][4 * rg + 2], (f16)acc[i][4 * rg + 3]};
            *(f16x4*)(prow + phys * 16 + (cl & 1) * 8) = h;
        }
    }
}

__device__ __forceinline__ void stage2_half(const char* region, const f16* wbaseX,
                                            const f16x8* wpre, int l31, int q5, int kh,
                                            f32x16& accP, f32x16& accQ) {
    const char* lbase = region + l31 * 1024;
#pragma unroll
    for (int kk = 0; kk < 16; kk++) {
        f16x8 wf = (kk < 4) ? wpre[kk & 3] : *(const f16x8*)(wbaseX + kk * 512);
        int s = kh * 16 + kk;
        int phys = ((s * 2 + q5) + l31) & 63;
        f16x8 af = *(const f16x8*)(lbase + phys * 16);
        if (kk & 1) accQ = MFMA32(af, wf, accQ);
        else        accP = MFMA32(af, wf, accP);
    }
}

__global__ __launch_bounds__(512, 4)
void fuse_kernel(const f16* __restrict__ left_t, const f16* __restrict__ rt2,
                 const f16* __restrict__ wt2, float* __restrict__ out) {
    __shared__ __align__(16) char lds[65536];

    int bid = blockIdx.x;        // 2048 = 32 br * 64 bt
    int br = bid >> 6, bt = bid & 63;
    int tid = threadIdx.x;
    int w = tid >> 6, lane = tid & 63;
    int q5 = lane >> 5, l31 = lane & 31, lx = lane & 15;
    int t_tile = w & 3, rg4 = w >> 2;      // stage1 roles
    int ntile = w & 3, kh = w >> 2;        // stage2 roles
    size_t rc0 = (size_t)br * 256;

    // ---- prologue: afr loads + W-A group0 + stage BOTH halves ----
    int g = bt * 4 + t_tile;
    const f16* ap = rt2 + (size_t)g * 4096 + (l31 * 2 + q5) * 8;
    f16x8 afr[8];
#pragma unroll
    for (int ks = 0; ks < 8; ks++) afr[ks] = *(const f16x8*)(ap + ks * 512);

    const f16* wbaseA = wt2 + (size_t)((0 * 4 + ntile) * 32 + kh * 16) * 512 + (l31 * 2 + q5) * 8;
    const f16* wbaseB = wt2 + (size_t)((1 * 4 + ntile) * 32 + kh * 16) * 512 + (l31 * 2 + q5) * 8;
    f16x8 wpreA[4];
#pragma unroll
    for (int u = 0; u < 4; u++) wpreA[u] = *(const f16x8*)(wbaseA + u * 512);

    // stage both c-halves: G in [0,4096) 16B chunks; X = G>>11
#pragma unroll
    for (int it = 0; it < 8; it++) {
        int G = it * 512 + tid;
        int X = G >> 11, h = G & 2047;
        int hrow = h >> 4, ch = h & 15;
        int r = hrow >> 4, cl = hrow & 15;
        f16x8 v = *(const f16x8*)(left_t + (rc0 + r * 32 + cl + X * 16) * 128 + ch * 8);
        *(f16x8*)(lds + X * 32768 + hrow * 256 + ((ch ^ (hrow & 15)) << 4)) = v;
    }
    __syncthreads();                                   // B1: staging visible

    // ---- round A ----
    f32x16 accA[2] = {};
    phase1_half((const f16*)lds, afr, rg4, l31, q5, lx, accA);
    __syncthreads();                                   // B2: done reading stgA
    phase2_half(lds, accA, rg4, t_tile, l31, q5);
    __syncthreads();                                   // B3: outerA visible

    f32x16 accP = {}, accQ = {};
    stage2_half(lds, wbaseA, wpreA, l31, q5, kh, accP, accQ);

    // W-B group0 preload (independent; compiler may hoist into stage2-A)
    f16x8 wpreB[4];
#pragma unroll
    for (int u = 0; u < 4; u++) wpreB[u] = *(const f16x8*)(wbaseB + u * 512);

    // ---- round B phase1 (no barrier needed: disjoint region, read-only) ----
    f32x16 accB[2] = {};
    phase1_half((const f16*)(lds + 32768), afr, rg4, l31, q5, lx, accB);
    __syncthreads();                                   // B4: stage2-A + phase1-B done
    phase2_half(lds + 32768, accB, rg4, t_tile, l31, q5);
    __syncthreads();                                   // B5: outerB visible
    stage2_half(lds + 32768, wbaseB, wpreB, l31, q5, kh, accP, accQ);

    f32x16 acc2;
#pragma unroll
    for (int v = 0; v < 16; v++) acc2[v] = accP[v] + accQ[v];
    __syncthreads();                                   // B6: before reduction overlay

    // ---- k-reduction: wave w+4 -> LDS, wave w adds ----
    if (w >= 4) {
        char* rb = lds + (w - 4) * 4096 + lane * 64;
#pragma unroll
        for (int u = 0; u < 4; u++) {
            f32x4 part = {acc2[4 * u], acc2[4 * u + 1], acc2[4 * u + 2], acc2[4 * u + 3]};
            *(f32x4*)(rb + u * 16) = part;
        }
    }
    __syncthreads();
    if (w < 4) {
        const char* rb = lds + w * 4096 + lane * 64;
#pragma unroll
        for (int u = 0; u < 4; u++) {
            f32x4 part = *(const f32x4*)(rb + u * 16);
#pragma unroll
            for (int v = 0; v < 4; v++) acc2[4 * u + v] += part[v];
        }
        // store: D row = p = (reg&3)+8*(reg>>2)+4*q5 ; col = cz = w*32 + l31
        int r0 = br * 8, t0 = bt * 4, cz = w * 32 + l31;
#pragma unroll
        for (int reg = 0; reg < 16; reg++) {
            int p = (reg & 3) + 8 * (reg >> 2) + 4 * q5;
            out[((size_t)((r0 + (p >> 2)) * R_DIM + t0 + (p & 3))) * CZ_DIM + cz] = acc2[reg];
        }
    }
}

// ---------------------------------------------------------------------------
extern "C" void kernel_launch(void* const* d_in, const int* in_sizes, int n_in,
                              void* d_out, int out_size, void* d_ws, size_t ws_size,
                              hipStream_t stream) {
    const float* msa = (const float*)d_in[0];
    const float* lw  = (const float*)d_in[1];
    const float* rw  = (const float*)d_in[2];
    const float* ow  = (const float*)d_in[3];
    char* ws = (char*)d_ws;
    f16* left_t = (f16*)(ws);                                   // 2 MB
    f16* rt2    = (f16*)(ws + (size_t)2 * 1024 * 1024);         // 2 MB
    f16* wt2    = (f16*)(ws + (size_t)4 * 1024 * 1024);         // 256 KB
    f16* wt_l   = (f16*)(ws + (size_t)4 * 1024 * 1024 + 262144);        // 16 KB
    f16* wt_r   = (f16*)(ws + (size_t)4 * 1024 * 1024 + 262144 + 16384);// 16 KB
    float* out  = (float*)d_out;

    prep_kernel<<<dim3(256), dim3(256), 0, stream>>>(lw, rw, ow, wt_l, wt_r, wt2);
    proj_kernel<<<dim3(512), dim3(256), 0, stream>>>(msa, wt_l, wt_r, left_t, rt2);
    fuse_kernel<<<dim3(2048), dim3(512), 0, stream>>>(left_t, rt2, wt2, out);
}

// Round 11
// 140.537 us; speedup vs baseline: 1.0292x; 1.0292x over previous
//
#include <hip/hip_runtime.h>
#include <stdint.h>

// Dims: msa[1,S,R,M] fp32 ; left_w/right_w[M,C] ; out_w[C*C,CZ] ; out[1,R,R,CZ] fp32
#define S_DIM 128
#define R_DIM 256
#define M_DIM 256
#define C_DIM 32
#define CZ_DIM 128
#define K2_DIM 1024  // C*C

typedef _Float16 f16;
typedef _Float16 f16x4 __attribute__((ext_vector_type(4)));
typedef _Float16 f16x8 __attribute__((ext_vector_type(8)));
typedef float f32x4 __attribute__((ext_vector_type(4)));
typedef float f32x16 __attribute__((ext_vector_type(16)));

#define MFMA32(a, b, c) __builtin_amdgcn_mfma_f32_32x32x16_f16(a, b, c, 0, 0, 0)

// ---------------------------------------------------------------------------
// prep: weights -> f16.  (identical to R10, correctness-proven)
//  wt_l/wt_r[c][m] (proj A-operands).
//  wt2 = out_w in c-half-major stage2 B-fragment order:
//   c = k2>>5, e = k2&31, X = c>>4 (c-half), cl = c&15,
//   k2ph = (e>>2)*64 + cl*4 + (e&3); kk = k2ph>>4, q5 = (k2ph>>3)&1, j = k2ph&7
//   idx = ((X*4+ntile)*32 + kk)*512 + (l31*2+q5)*8 + j   -> 1KB/wave coalesced.
// ---------------------------------------------------------------------------
__global__ void prep_kernel(const float* __restrict__ lw, const float* __restrict__ rw,
                            const float* __restrict__ ow,
                            f16* __restrict__ wt_l, f16* __restrict__ wt_r,
                            f16* __restrict__ wt2) {
    int idx = blockIdx.x * blockDim.x + threadIdx.x;
    int stride = gridDim.x * blockDim.x;
    for (int i = idx; i < CZ_DIM * K2_DIM; i += stride) {
        int cz = i >> 10, k2 = i & 1023;
        int c = k2 >> 5, e = k2 & 31;
        int X = c >> 4, cl = c & 15;
        int k2ph = ((e >> 2) << 6) + (cl << 2) + (e & 3);
        int kk = k2ph >> 4, q5 = (k2ph >> 3) & 1, j = k2ph & 7;
        int ntile = cz >> 5, l31 = cz & 31;
        wt2[(((X * 4 + ntile) * 32) + kk) * 512 + (l31 * 2 + q5) * 8 + j] =
            (f16)ow[k2 * CZ_DIM + cz];
    }
    for (int i = idx; i < C_DIM * M_DIM; i += stride) {
        int c = i >> 8, m = i & 255;
        wt_l[i] = (f16)lw[m * C_DIM + c];
        wt_r[i] = (f16)rw[m * C_DIM + c];
    }
}

// ---------------------------------------------------------------------------
// proj (unchanged, near HBM floor): left_t[(r*32+c)][s] row-major;
// rt2 in stage1 A-fragment-major order.
// ---------------------------------------------------------------------------
__global__ __launch_bounds__(256, 4)
void proj_kernel(const float* __restrict__ msa, const f16* __restrict__ wt_l,
                 const f16* __restrict__ wt_r,
                 f16* __restrict__ left_t, f16* __restrict__ rt2) {
    int bid = blockIdx.x;            // 512 = 256 r * 2 s-halves
    int r  = bid >> 1;
    int s0 = (bid & 1) << 6;
    int tid = threadIdx.x;
    int w = tid >> 6;
    int lane = tid & 63;
    int q = lane >> 4, li = lane & 15;

    int s_col = s0 + w * 16 + li;
    const f32x4* bp = (const f32x4*)(msa + ((size_t)s_col * R_DIM + r) * M_DIM + q * 8);

    f32x4 b[16];
#pragma unroll
    for (int ks = 0; ks < 8; ks++) { b[2 * ks] = bp[ks * 8]; b[2 * ks + 1] = bp[ks * 8 + 1]; }

    f32x4 aL0 = {0,0,0,0}, aL1 = {0,0,0,0}, aR0 = {0,0,0,0}, aR1 = {0,0,0,0};
#pragma unroll
    for (int ks = 0; ks < 8; ks++) {
        f16x8 bf;
#pragma unroll
        for (int u = 0; u < 4; u++) { bf[u] = (f16)b[2*ks][u]; bf[4 + u] = (f16)b[2*ks+1][u]; }
        const f16* a0 = wt_l + li * M_DIM + ks * 32 + q * 8;
        const f16* a1 = wt_r + li * M_DIM + ks * 32 + q * 8;
        f16x8 al0 = *(const f16x8*)(a0);
        f16x8 al1 = *(const f16x8*)(a0 + 16 * M_DIM);
        f16x8 ar0 = *(const f16x8*)(a1);
        f16x8 ar1 = *(const f16x8*)(a1 + 16 * M_DIM);
        aL0 = __builtin_amdgcn_mfma_f32_16x16x32_f16(al0, bf, aL0, 0, 0, 0);
        aL1 = __builtin_amdgcn_mfma_f32_16x16x32_f16(al1, bf, aL1, 0, 0, 0);
        aR0 = __builtin_amdgcn_mfma_f32_16x16x32_f16(ar0, bf, aR0, 0, 0, 0);
        aR1 = __builtin_amdgcn_mfma_f32_16x16x32_f16(ar1, bf, aR1, 0, 0, 0);
    }
    int ks_s = s_col >> 4, q5_s = (s_col >> 3) & 1, j_s = s_col & 7;
    int sbase = (r * 8 + ks_s) * 512 + q5_s * 8 + j_s;
#pragma unroll
    for (int reg = 0; reg < 4; reg++) {
        int c0 = q * 4 + reg;
        left_t[(r * C_DIM + c0) * S_DIM + s_col]      = (f16)aL0[reg];
        left_t[(r * C_DIM + c0 + 16) * S_DIM + s_col] = (f16)aL1[reg];
        rt2[sbase + c0 * 16]        = (f16)aR0[reg];
        rt2[sbase + (c0 + 16) * 16] = (f16)aR1[reg];
    }
}

// ---------------------------------------------------------------------------
// fuse_kernel v7: c-split with SPILL-PROOF ordering.
//  Index math identical to v6 (R10, passing). Order changed so afr dies at
//  phase1-B (before any stage2) and no wpre arrays exist:
//   prologue -> B1 -> p1A -> B2 -> [p2A ; p1B] -> B3 -> [s2A ; p2B] -> B4
//   -> s2B -> reduction.
//  Peak live ~105 VGPR < 128 cap (launch_bounds(512,4)).
// ---------------------------------------------------------------------------
__device__ __forceinline__ void phase1_half(const f16* stg, const f16x8* afr,
                                            int rg4, int l31, int q5, int lx,
                                            f32x16* acc) {
#pragma unroll
    for (int i = 0; i < 2; i++) {
        const f16* bbase = stg + ((rg4 * 2 + i) * 32 + l31) * 128;
#pragma unroll
        for (int ks = 0; ks < 8; ks++) {
            f16x8 bfr = *(const f16x8*)(bbase + (((2 * ks + q5) ^ lx) << 3));
            acc[i] = MFMA32(afr[ks], bfr, acc[i]);
        }
    }
}

__device__ __forceinline__ void phase2_half(char* region, const f32x16* acc,
                                            int rg4, int t_tile, int l31, int q5) {
    int cl = l31 & 15, r_hi = l31 >> 4;
#pragma unroll
    for (int i = 0; i < 2; i++) {
        int p = ((rg4 * 2 + i) * 2 + r_hi) * 4 + t_tile;   // pair row 0..31
        char* prow = region + p * 1024;
#pragma unroll
        for (int rg = 0; rg < 4; rg++) {
            int chunk = (2 * rg + q5) * 8 + (cl >> 1);
            int phys = (chunk + p) & 63;
            f16x4 h = {(f16)acc[i][4 * rg], (f16)acc[i][4 * rg + 1],
                       (f16)acc[i][4 * rg + 2], (f16)acc[i][4 * rg + 3]};
            *(f16x4*)(prow + phys * 16 + (cl & 1) * 8) = h;
        }
    }
}

__device__ __forceinline__ void stage2_half(const char* region, const f16* wbaseX,
                                            int l31, int q5, int kh,
                                            f32x16& accP, f32x16& accQ) {
    const char* lbase = region + l31 * 1024;
#pragma unroll
    for (int kk = 0; kk < 16; kk++) {
        f16x8 wf = *(const f16x8*)(wbaseX + kk * 512);
        int s = kh * 16 + kk;
        int phys = ((s * 2 + q5) + l31) & 63;
        f16x8 af = *(const f16x8*)(lbase + phys * 16);
        if (kk & 1) accQ = MFMA32(af, wf, accQ);
        else        accP = MFMA32(af, wf, accP);
    }
}

__global__ __launch_bounds__(512, 4)
void fuse_kernel(const f16* __restrict__ left_t, const f16* __restrict__ rt2,
                 const f16* __restrict__ wt2, float* __restrict__ out) {
    __shared__ __align__(16) char lds[65536];

    int bid = blockIdx.x;        // 2048 = 32 br * 64 bt
    int br = bid >> 6, bt = bid & 63;
    int tid = threadIdx.x;
    int w = tid >> 6, lane = tid & 63;
    int q5 = lane >> 5, l31 = lane & 31, lx = lane & 15;
    int t_tile = w & 3, rg4 = w >> 2;      // stage1 roles
    int ntile = w & 3, kh = w >> 2;        // stage2 roles
    size_t rc0 = (size_t)br * 256;

    // ---- prologue: afr loads + stage BOTH c-halves ----
    int g = bt * 4 + t_tile;
    const f16* ap = rt2 + (size_t)g * 4096 + (l31 * 2 + q5) * 8;
    f16x8 afr[8];
#pragma unroll
    for (int ks = 0; ks < 8; ks++) afr[ks] = *(const f16x8*)(ap + ks * 512);

    const f16* wbaseA = wt2 + (size_t)((0 * 4 + ntile) * 32 + kh * 16) * 512 + (l31 * 2 + q5) * 8;
    const f16* wbaseB = wt2 + (size_t)((1 * 4 + ntile) * 32 + kh * 16) * 512 + (l31 * 2 + q5) * 8;

    // stage both c-halves: G in [0,4096) 16B chunks; X = G>>11
#pragma unroll
    for (int it = 0; it < 8; it++) {
        int G = it * 512 + tid;
        int X = G >> 11, h = G & 2047;
        int hrow = h >> 4, ch = h & 15;
        int r = hrow >> 4, cl = hrow & 15;
        f16x8 v = *(const f16x8*)(left_t + (rc0 + r * 32 + cl + X * 16) * 128 + ch * 8);
        *(f16x8*)(lds + X * 32768 + hrow * 256 + ((ch ^ (hrow & 15)) << 4)) = v;
    }
    __syncthreads();                                   // B1: staging visible

    // ---- phase1-A ----
    f32x16 accA[2] = {};
    phase1_half((const f16*)lds, afr, rg4, l31, q5, lx, accA);
    __syncthreads();                                   // B2: stgA reads done

    // ---- phase2-A (writes region A)  ∥  phase1-B (reads region B) ----
    phase2_half(lds, accA, rg4, t_tile, l31, q5);
    f32x16 accB[2] = {};
    phase1_half((const f16*)(lds + 32768), afr, rg4, l31, q5, lx, accB);
    __syncthreads();                                   // B3: outerA visible, stgB reads done

    // ---- stage2-A (reads region A, L2 W)  ∥  phase2-B (writes region B) ----
    f32x16 accP = {}, accQ = {};
    stage2_half(lds, wbaseA, l31, q5, kh, accP, accQ);
    phase2_half(lds + 32768, accB, rg4, t_tile, l31, q5);
    __syncthreads();                                   // B4: outerB visible, outerA reads done

    // ---- stage2-B ----
    stage2_half(lds + 32768, wbaseB, l31, q5, kh, accP, accQ);

    f32x16 acc2;
#pragma unroll
    for (int v = 0; v < 16; v++) acc2[v] = accP[v] + accQ[v];

    // ---- k-reduction: wave w+4 -> region A (free since B4), wave w adds ----
    if (w >= 4) {
        char* rb = lds + (w - 4) * 4096 + lane * 64;
#pragma unroll
        for (int u = 0; u < 4; u++) {
            f32x4 part = {acc2[4 * u], acc2[4 * u + 1], acc2[4 * u + 2], acc2[4 * u + 3]};
            *(f32x4*)(rb + u * 16) = part;
        }
    }
    __syncthreads();                                   // B5: handoff
    if (w < 4) {
        const char* rb = lds + w * 4096 + lane * 64;
#pragma unroll
        for (int u = 0; u < 4; u++) {
            f32x4 part = *(const f32x4*)(rb + u * 16);
#pragma unroll
            for (int v = 0; v < 4; v++) acc2[4 * u + v] += part[v];
        }
        // store: D row = p = (reg&3)+8*(reg>>2)+4*q5 ; col = cz = w*32 + l31
        int r0 = br * 8, t0 = bt * 4, cz = w * 32 + l31;
#pragma unroll
        for (int reg = 0; reg < 16; reg++) {
            int p = (reg & 3) + 8 * (reg >> 2) + 4 * q5;
            out[((size_t)((r0 + (p >> 2)) * R_DIM + t0 + (p & 3))) * CZ_DIM + cz] = acc2[reg];
        }
    }
}

// ---------------------------------------------------------------------------
extern "C" void kernel_launch(void* const* d_in, const int* in_sizes, int n_in,
                              void* d_out, int out_size, void* d_ws, size_t ws_size,
                              hipStream_t stream) {
    const float* msa = (const float*)d_in[0];
    const float* lw  = (const float*)d_in[1];
    const float* rw  = (const float*)d_in[2];
    const float* ow  = (const float*)d_in[3];
    char* ws = (char*)d_ws;
    f16* left_t = (f16*)(ws);                                   // 2 MB
    f16* rt2    = (f16*)(ws + (size_t)2 * 1024 * 1024);         // 2 MB
    f16* wt2    = (f16*)(ws + (size_t)4 * 1024 * 1024);         // 256 KB
    f16* wt_l   = (f16*)(ws + (size_t)4 * 1024 * 1024 + 262144);        // 16 KB
    f16* wt_r   = (f16*)(ws + (size_t)4 * 1024 * 1024 + 262144 + 16384);// 16 KB
    float* out  = (float*)d_out;

    prep_kernel<<<dim3(256), dim3(256), 0, stream>>>(lw, rw, ow, wt_l, wt_r, wt2);
    proj_kernel<<<dim3(512), dim3(256), 0, stream>>>(msa, wt_l, wt_r, left_t, rt2);
    fuse_kernel<<<dim3(2048), dim3(512), 0, stream>>>(left_t, rt2, wt2, out);
}